// Round 7
// baseline (423.343 us; speedup 1.0000x reference)
//
#include <hip/hip_runtime.h>

// Problem constants
constexpr int Hd = 512;
constexpr int Bd = 64;
constexpr int Sd = 2048;

constexpr int BM = 128;   // block rows (2 waves)
constexpr int BN = 128;   // block cols (2 waves)
constexpr int BK = 32;    // K per step (one MFMA k-slab)

typedef __bf16 bf16x8 __attribute__((ext_vector_type(8)));
typedef float  f32x4  __attribute__((ext_vector_type(4)));
typedef unsigned short u16x8 __attribute__((ext_vector_type(8)));

__device__ __forceinline__ unsigned short f2bf(float f){
  __bf16 h = (__bf16)f;
  return __builtin_bit_cast(unsigned short, h);
}

__device__ __forceinline__ float fast_tanh(float x){
  // tanh(x) = 1 - 2/(e^{2x}+1); saturates correctly
  float e = __expf(2.0f * x);
  return 1.0f - 2.0f * __builtin_amdgcn_rcpf(e + 1.0f);
}

__device__ __forceinline__ bf16x8 cvt8(f32x4 lo, f32x4 hi){
  bf16x8 r;
  r[0]=(__bf16)lo[0]; r[1]=(__bf16)lo[1]; r[2]=(__bf16)lo[2]; r[3]=(__bf16)lo[3];
  r[4]=(__bf16)hi[0]; r[5]=(__bf16)hi[1]; r[6]=(__bf16)hi[2]; r[7]=(__bf16)hi[3];
  return r;
}

// Prologue: blocks [0,128) convert Wr f32->bf16 row-major; blocks [128,192) qproj
__global__ __launch_bounds__(256) void prologue_kernel(const float* __restrict__ Wr,
                                                       unsigned short* __restrict__ Wrb,
                                                       const float* __restrict__ query,
                                                       const float* __restrict__ Wq,
                                                       const float* __restrict__ bq,
                                                       float* __restrict__ qout){
  if (blockIdx.x < 128){
    int base = (blockIdx.x*256 + (int)threadIdx.x) * 8;
    f32x4 v0 = *(const f32x4*)(Wr + base);
    f32x4 v1 = *(const f32x4*)(Wr + base + 4);
    u16x8 o;
    o[0]=f2bf(v0[0]); o[1]=f2bf(v0[1]); o[2]=f2bf(v0[2]); o[3]=f2bf(v0[3]);
    o[4]=f2bf(v1[0]); o[5]=f2bf(v1[1]); o[6]=f2bf(v1[2]); o[7]=f2bf(v1[3]);
    *(u16x8*)(Wrb + base) = o;
  } else {
    int b   = blockIdx.x - 128;
    int tid = threadIdx.x;
    __shared__ float qs[Hd];
    for (int i = tid; i < Hd; i += 256) qs[i] = query[b*Hd + i];
    __syncthreads();
    for (int o = tid; o < Hd; o += 256){
      const float* w = Wq + (size_t)o*Hd;
      float s = 0.f;
      #pragma unroll 4
      for (int k = 0; k < Hd; k += 4){
        f32x4 wv = *(const f32x4*)(w + k);
        s += wv[0]*qs[k] + wv[1]*qs[k+1] + wv[2]*qs[k+2] + wv[3]*qs[k+3];
      }
      qout[b*Hd + o] = s + bq[o];
    }
  }
}

// Per batch b: C[o][s] = sum_h Wr[o][h] * ref[b][s][h]; fused tanh/V logits.
// NO LDS, NO barriers: MFMA fragments loaded directly from global.
//  A-frag: lane l -> Wrb[row = l&15][k = (l>>4)*8 + j]   (16B contiguous bf16)
//  B-frag: lane l -> ref [col = l&15][same k]            (32B contiguous f32 + cvt)
// (frag layouts validated by rounds 1-6 passing with the same epilogue mapping)
__global__ __launch_bounds__(256) void fused_kernel(const float* __restrict__ ref,
                                                    const unsigned short* __restrict__ Wrb,
                                                    const float* __restrict__ br,
                                                    const float* __restrict__ V,
                                                    const float* __restrict__ qbuf,
                                                    float* __restrict__ out,     // [B][H][S]
                                                    float* __restrict__ logits){ // [B][S]
  // Bijective XCD swizzle (nwg=4096 divisible by 8): 4 mt-blocks sharing a ref
  // panel land consecutively on the SAME XCD.
  const int bid = blockIdx.x;
  const int wid = (bid & 7) * (gridDim.x >> 3) + (bid >> 3);
  const int mt  = wid & 3;
  const int nt  = (wid >> 2) & 15;
  const int bb  = wid >> 6;
  const int m0  = mt * BM;
  const int n0  = nt * BN;

  const int tid  = threadIdx.x;
  const int lane = tid & 63;
  const int wave = tid >> 6;
  const int wm   = wave >> 1;   // 2x2 wave grid, each wave owns 64x64 of C
  const int wn   = wave & 1;

  const int r16 = lane & 15;        // frag row (A) / col (B)
  const int kg8 = (lane >> 4) * 8;  // k-offset within the 32-wide slab

  const unsigned short* Abase = Wrb + (size_t)(m0 + wm*64 + r16)*Hd + kg8;           // + mi*16*Hd + kt
  const float*          Bbase = ref + ((size_t)bb*Sd + (n0 + wn*64 + r16))*Hd + kg8; // + ni*16*Hd + kt

  f32x4 acc[4][4];
  #pragma unroll
  for (int i = 0; i < 4; ++i)
    #pragma unroll
    for (int j = 0; j < 4; ++j)
      acc[i][j] = f32x4{0.f, 0.f, 0.f, 0.f};

  bf16x8 Af[4];        // A frags for current step (single-buffered: L2-hot)
  f32x4  Br[2][4][2];  // B raw f32, double-buffered across steps

  auto loadA = [&](int kt){
    #pragma unroll
    for (int mi = 0; mi < 4; ++mi)
      Af[mi] = *(const bf16x8*)(Abase + (size_t)mi*16*Hd + kt);
  };
  // u is a compile-time unroll index -> static Br indexing (no scratch)
  auto loadB = [&](int u, int kt){
    #pragma unroll
    for (int ni = 0; ni < 4; ++ni){
      Br[u][ni][0] = *(const f32x4*)(Bbase + (size_t)ni*16*Hd + kt);
      Br[u][ni][1] = *(const f32x4*)(Bbase + (size_t)ni*16*Hd + kt + 4);
    }
  };

  loadB(0, 0);                       // B(0) in flight
  #pragma unroll 1
  for (int t2 = 0; t2 < 8; ++t2){
    #pragma unroll
    for (int u = 0; u < 2; ++u){
      const int t  = t2*2 + u;
      const int kc = t * BK;
      const int kn = (t + 1 < 16 ? t + 1 : 15) * BK;  // last reload is redundant, harmless
      loadA(kc);                     // A(t): L1/L2-hot, short latency
      loadB(u ^ 1, kn);              // B(t+1): stays in flight across this step's MFMAs
      #pragma unroll
      for (int ni = 0; ni < 4; ++ni){
        bf16x8 Bf = cvt8(Br[u][ni][0], Br[u][ni][1]);  // waits only on B(t)[ni]
        #pragma unroll
        for (int mi = 0; mi < 4; ++mi)
          acc[mi][ni] = __builtin_amdgcn_mfma_f32_16x16x32_bf16(Af[mi], Bf, acc[mi][ni], 0, 0, 0);
      }
    }
  }

  // ---- epilogue: +br, NT-store ref_t, fused tanh/V column sums ----
  const int col0 = n0 + wn*64;
  const int row0 = m0 + wm*64;
  const int cl   = lane & 15;          // C/D: col = lane&15
  const int rgrp = (lane >> 4) * 4;    //      row = (lane>>4)*4 + j
  const float* qrow = qbuf + bb*Hd;
  float colsum[4] = {0.f, 0.f, 0.f, 0.f};
  float* outb = out + (size_t)bb*Hd*Sd;

  #pragma unroll
  for (int mi = 0; mi < 4; ++mi){
    #pragma unroll
    for (int j = 0; j < 4; ++j){
      int o = row0 + mi*16 + rgrp + j;
      float brv = br[o];
      float qv  = qrow[o];
      float vv  = V[o];
      float* orow = outb + (size_t)o*Sd + col0;
      #pragma unroll
      for (int ni = 0; ni < 4; ++ni){
        float c = acc[mi][ni][j] + brv;
        __builtin_nontemporal_store(c, &orow[ni*16 + cl]);  // don't thrash L2/L3
        colsum[ni] += vv * fast_tanh(qv + c);
      }
    }
  }

  // reduce over the wave's 64 rows: lanes sharing (lane&15) are l, l^16, l^32, l^48
  #pragma unroll
  for (int ni = 0; ni < 4; ++ni){
    colsum[ni] += __shfl_xor(colsum[ni], 16);
    colsum[ni] += __shfl_xor(colsum[ni], 32);
  }
  if (lane < 16){
    float* lrow = logits + (size_t)bb*Sd + col0;
    #pragma unroll
    for (int ni = 0; ni < 4; ++ni)
      atomicAdd(lrow + ni*16 + cl, colsum[ni]);
  }
}

extern "C" void kernel_launch(void* const* d_in, const int* in_sizes, int n_in,
                              void* d_out, int out_size, void* d_ws, size_t ws_size,
                              hipStream_t stream){
  const float* query = (const float*)d_in[0];
  const float* ref   = (const float*)d_in[1];
  const float* Wq    = (const float*)d_in[2];
  const float* bq    = (const float*)d_in[3];
  const float* Wr    = (const float*)d_in[4];
  const float* br    = (const float*)d_in[5];
  const float* V     = (const float*)d_in[6];

  float* out    = (float*)d_out;
  float* logits = out + (size_t)Bd*Hd*Sd;   // second output, concatenated flat
  float* qbuf   = (float*)d_ws;                                      // [B][H] f32 = 128 KB
  unsigned short* Wrb = (unsigned short*)((char*)d_ws + 128*1024);   // [H][H] bf16 = 512 KB

  hipMemsetAsync(logits, 0, (size_t)Bd*Sd*sizeof(float), stream);
  prologue_kernel<<<192, 256, 0, stream>>>(Wr, Wrb, query, Wq, bq, qbuf);

  // grid: 64 batches x (16 n-tiles x 4 m-tiles), XCD-swizzled in-kernel
  fused_kernel<<<Bd*64, 256, 0, stream>>>(ref, Wrb, br, V, qbuf, out, logits);
}

// Round 8
// 249.216 us; speedup vs baseline: 1.6987x; 1.6987x over previous
//
#include <hip/hip_runtime.h>

// Problem constants
constexpr int Hd = 512;
constexpr int Bd = 64;
constexpr int Sd = 2048;

constexpr int BM = 128;
constexpr int BN = 128;
constexpr int BK = 32;

typedef __bf16 bf16x8 __attribute__((ext_vector_type(8)));
typedef float  f32x4  __attribute__((ext_vector_type(4)));
typedef unsigned short u16x8 __attribute__((ext_vector_type(8)));

typedef const __attribute__((address_space(1))) unsigned int* gas1_t;
typedef __attribute__((address_space(3))) unsigned int* las3_t;

__device__ __forceinline__ unsigned short f2bf(float f){
  __bf16 h = (__bf16)f;
  return __builtin_bit_cast(unsigned short, h);
}

__device__ __forceinline__ float fast_tanh(float x){
  float e = __expf(2.0f * x);
  return 1.0f - 2.0f * __builtin_amdgcn_rcpf(e + 1.0f);
}

__device__ __forceinline__ bf16x8 cvt8(f32x4 lo, f32x4 hi){
  bf16x8 r;
  r[0]=(__bf16)lo[0]; r[1]=(__bf16)lo[1]; r[2]=(__bf16)lo[2]; r[3]=(__bf16)lo[3];
  r[4]=(__bf16)hi[0]; r[5]=(__bf16)hi[1]; r[6]=(__bf16)hi[2]; r[7]=(__bf16)hi[3];
  return r;
}

// Prologue: blocks [0,128) convert Wr f32->bf16 row-major; blocks [128,192) qproj
__global__ __launch_bounds__(256) void prologue_kernel(const float* __restrict__ Wr,
                                                       unsigned short* __restrict__ Wrb,
                                                       const float* __restrict__ query,
                                                       const float* __restrict__ Wq,
                                                       const float* __restrict__ bq,
                                                       float* __restrict__ qout){
  if (blockIdx.x < 128){
    int base = (blockIdx.x*256 + (int)threadIdx.x) * 8;
    f32x4 v0 = *(const f32x4*)(Wr + base);
    f32x4 v1 = *(const f32x4*)(Wr + base + 4);
    u16x8 o;
    o[0]=f2bf(v0[0]); o[1]=f2bf(v0[1]); o[2]=f2bf(v0[2]); o[3]=f2bf(v0[3]);
    o[4]=f2bf(v1[0]); o[5]=f2bf(v1[1]); o[6]=f2bf(v1[2]); o[7]=f2bf(v1[3]);
    *(u16x8*)(Wrb + base) = o;
  } else {
    int b   = blockIdx.x - 128;
    int tid = threadIdx.x;
    __shared__ float qs[Hd];
    for (int i = tid; i < Hd; i += 256) qs[i] = query[b*Hd + i];
    __syncthreads();
    for (int o = tid; o < Hd; o += 256){
      const float* w = Wq + (size_t)o*Hd;
      float s = 0.f;
      #pragma unroll 4
      for (int k = 0; k < Hd; k += 4){
        f32x4 wv = *(const f32x4*)(w + k);
        s += wv[0]*qs[k] + wv[1]*qs[k+1] + wv[2]*qs[k+2] + wv[3]*qs[k+3];
      }
      qout[b*Hd + o] = s + bq[o];
    }
  }
}

// Per batch b: C[o][s] = sum_h Wr[o][h] * ref[b][s][h]; fused tanh/V logits.
// B (ref) staged f32 via global_load_lds with source-side XOR pre-swizzle;
// A-frags direct from L2-hot Wrb; counted vmcnt keeps the HBM stream deep.
__global__ __launch_bounds__(256, 3) void fused_kernel(const float* __restrict__ ref,
                                                       const unsigned short* __restrict__ Wrb,
                                                       const float* __restrict__ br,
                                                       const float* __restrict__ V,
                                                       const float* __restrict__ qbuf,
                                                       float* __restrict__ out,     // [B][H][S]
                                                       float* __restrict__ logits){ // [B][S]
  // Bijective XCD swizzle (nwg=4096 divisible by 8)
  const int bid = blockIdx.x;
  const int wid = (bid & 7) * (gridDim.x >> 3) + (bid >> 3);
  const int mt  = wid & 3;
  const int nt  = (wid >> 2) & 15;
  const int bb  = wid >> 6;
  const int m0  = mt * BM;
  const int n0  = nt * BN;

  const int tid  = threadIdx.x;
  const int lane = tid & 63;
  const int wave = tid >> 6;
  const int wm   = wave >> 1;   // 2x2 wave grid, each wave owns 64x64 of C
  const int wn   = wave & 1;

  __shared__ float Bs[2][BN*BK];   // 2 x 16 KB, rows of 32 f32 (128B), phys slot = logical^(row&7)

  f32x4 acc[4][4];
  #pragma unroll
  for (int i = 0; i < 4; ++i)
    #pragma unroll
    for (int j = 0; j < 4; ++j)
      acc[i][j] = f32x4{0.f, 0.f, 0.f, 0.f};

  // ---- B staging geometry (global_load_lds, 4 calls/tile) ----
  // call c: segment g = c*4+wave covers rows 8g..8g+7; lane l -> row 8g+(l>>3),
  // phys 16B-slot l&7; logical slot sl = (l&7)^(row&7); src = ref[row][kt+sl*4].
  const float* bsrc[4];
  float*       bdst0[4];
  #pragma unroll
  for (int c = 0; c < 4; ++c){
    int g   = c*4 + wave;
    int row = g*8 + (lane >> 3);
    int sl  = (lane & 7) ^ (row & 7);
    bsrc[c]  = ref + ((size_t)bb*Sd + n0 + row)*Hd + sl*4;
    bdst0[c] = &Bs[0][g*256];        // wave-uniform base; HW adds lane*16
  }
  auto stageB = [&](int buf, int kt){
    #pragma unroll
    for (int c = 0; c < 4; ++c){
      __builtin_amdgcn_global_load_lds((gas1_t)(bsrc[c] + kt),
                                       (las3_t)(bdst0[c] + buf*(BN*BK)),
                                       16, 0, 0);
    }
  };

  // ---- A direct-frag geometry ----
  const int r16 = lane & 15;
  const int kg8 = (lane >> 4) * 8;
  const unsigned short* Abase = Wrb + (size_t)(m0 + wm*64 + r16)*Hd + kg8;
  auto loadA = [&](bf16x8 (&A)[4], int kt){
    #pragma unroll
    for (int mi = 0; mi < 4; ++mi)
      A[mi] = *(const bf16x8*)(Abase + (size_t)mi*16*Hd + kt);
  };

  // ---- B frag read (swizzled) ----
  const float* brd[4][2];
  #pragma unroll
  for (int ni = 0; ni < 4; ++ni){
    int r  = wn*64 + ni*16 + r16;
    int s0 = (lane >> 4) * 2;
    brd[ni][0] = &Bs[0][r*32 + ((s0     ^ (r & 7)) << 2)];
    brd[ni][1] = &Bs[0][r*32 + (((s0+1) ^ (r & 7)) << 2)];
  }

  bf16x8 Af0[4], Af1[4];

  auto iterstep = [&](bf16x8 (&Ac)[4], bf16x8 (&An)[4], int buf, int t){
    // B(t) gll retired (newest 8 = A(t) + B(t+1) may remain in flight)
    asm volatile("s_waitcnt vmcnt(8)" ::: "memory");
    __builtin_amdgcn_s_barrier();                 // all waves' B(t) staged
    f32x4 Br[4][2];
    #pragma unroll
    for (int ni = 0; ni < 4; ++ni){
      Br[ni][0] = *(const f32x4*)(brd[ni][0] + buf*(BN*BK));
      Br[ni][1] = *(const f32x4*)(brd[ni][1] + buf*(BN*BK));
    }
    loadA(An, (t+1 < 16 ? t+1 : 15) * BK);        // dist-1, L2-hot
    asm volatile("s_waitcnt lgkmcnt(0)" ::: "memory");
    __builtin_amdgcn_s_barrier();                 // all waves done reading buf
    stageB(buf, (t+2 < 16 ? t+2 : 15) * BK);      // refill buf for t+2 (clamped tail: benign)
    #pragma unroll
    for (int ni = 0; ni < 4; ++ni){
      bf16x8 Bf = cvt8(Br[ni][0], Br[ni][1]);
      #pragma unroll
      for (int mi = 0; mi < 4; ++mi)
        acc[mi][ni] = __builtin_amdgcn_mfma_f32_16x16x32_bf16(Ac[mi], Bf, acc[mi][ni], 0, 0, 0);
    }
  };

  // pipeline prologue (order matters for the vmcnt(8) arithmetic: B(0), A(0), B(1))
  stageB(0, 0);
  loadA(Af0, 0);
  stageB(1, BK);

  #pragma unroll 1
  for (int t2 = 0; t2 < 8; ++t2){
    iterstep(Af0, Af1, 0, t2*2);
    iterstep(Af1, Af0, 1, t2*2 + 1);
  }
  asm volatile("s_waitcnt vmcnt(0)" ::: "memory");  // drain trailing clamped gll

  // ---- epilogue: +br, NT-store ref_t, fused tanh/V column sums ----
  const int col0 = n0 + wn*64;
  const int row0 = m0 + wm*64;
  const int cl   = lane & 15;          // C/D: col = lane&15
  const int rgrp = (lane >> 4) * 4;    //      row = (lane>>4)*4 + j
  const float* qrow = qbuf + bb*Hd;
  float colsum[4] = {0.f, 0.f, 0.f, 0.f};
  float* outb = out + (size_t)bb*Hd*Sd;

  #pragma unroll
  for (int mi = 0; mi < 4; ++mi){
    #pragma unroll
    for (int j = 0; j < 4; ++j){
      int o = row0 + mi*16 + rgrp + j;
      float brv = br[o];
      float qv  = qrow[o];
      float vv  = V[o];
      float* orow = outb + (size_t)o*Sd + col0;
      #pragma unroll
      for (int ni = 0; ni < 4; ++ni){
        float c = acc[mi][ni][j] + brv;
        __builtin_nontemporal_store(c, &orow[ni*16 + cl]);  // don't thrash L2/L3
        colsum[ni] += vv * fast_tanh(qv + c);
      }
    }
  }

  // reduce over the wave's 64 rows: lanes sharing (lane&15) are l, l^16, l^32, l^48
  #pragma unroll
  for (int ni = 0; ni < 4; ++ni){
    colsum[ni] += __shfl_xor(colsum[ni], 16);
    colsum[ni] += __shfl_xor(colsum[ni], 32);
  }
  if (lane < 16){
    float* lrow = logits + (size_t)bb*Sd + col0;
    #pragma unroll
    for (int ni = 0; ni < 4; ++ni)
      atomicAdd(lrow + ni*16 + cl, colsum[ni]);
  }
}

extern "C" void kernel_launch(void* const* d_in, const int* in_sizes, int n_in,
                              void* d_out, int out_size, void* d_ws, size_t ws_size,
                              hipStream_t stream){
  const float* query = (const float*)d_in[0];
  const float* ref   = (const float*)d_in[1];
  const float* Wq    = (const float*)d_in[2];
  const float* bq    = (const float*)d_in[3];
  const float* Wr    = (const float*)d_in[4];
  const float* br    = (const float*)d_in[5];
  const float* V     = (const float*)d_in[6];

  float* out    = (float*)d_out;
  float* logits = out + (size_t)Bd*Hd*Sd;   // second output, concatenated flat
  float* qbuf   = (float*)d_ws;                                      // [B][H] f32 = 128 KB
  unsigned short* Wrb = (unsigned short*)((char*)d_ws + 128*1024);   // [H][H] bf16 = 512 KB

  hipMemsetAsync(logits, 0, (size_t)Bd*Sd*sizeof(float), stream);
  prologue_kernel<<<192, 256, 0, stream>>>(Wr, Wrb, query, Wq, bq, qbuf);

  // grid: 64 batches x (16 n-tiles x 4 m-tiles), XCD-swizzled in-kernel
  fused_kernel<<<Bd*64, 256, 0, stream>>>(ref, Wrb, br, V, qbuf, out, logits);
}